// Round 2
// baseline (93.943 us; speedup 1.0000x reference)
//
#include <hip/hip_runtime.h>
#include <math.h>

#define GH 5
#define GW 10
#define HW 50            // GH*GW
#define CPA 85           // channels per anchor (5 + 80)
#define SLICE 12750      // 255 * 50 floats per batch
#define NT 8             // targets per batch
#define NF4 3187         // (SLICE-2)/4 float4s per batch
#define IOU_THR 0.3f

__device__ __forceinline__ float softplusf(float x) {
    return fmaxf(x, 0.0f) + log1pf(expf(-fabsf(x)));   // log(1+e^x), stable
}
__device__ __forceinline__ float sigmoidf(float x) {
    return 1.0f / (1.0f + expf(-x));
}

__global__ __launch_bounds__(256) void yolo_main(
    const float* __restrict__ preds,
    const float* __restrict__ targets,
    const float* __restrict__ anchors,
    float* __restrict__ acc)   // acc[0]=coord_raw acc[1]=obj acc[2]=noobj_raw acc[3]=cls_raw
{
    __shared__ float ptile[NT][88];          // gathered 85 channels per target
    __shared__ float stgt[NT][4];
    __shared__ int   slo[NT];                // first global-channel of best anchor
    __shared__ int   syx[NT];                // cell index gy*GW+gx (or -1)
    __shared__ int   scls[NT];
    __shared__ int   svalid[NT];
    __shared__ unsigned char tmask[52];      // per-yx bitmask of matching targets
    __shared__ unsigned long long ymask_sh;
    __shared__ float Ssh;
    __shared__ float wsum[4];
    __shared__ float accS[4];

    const int b   = blockIdx.x;
    const int tid = threadIdx.x;
    if (tid < 4) accS[tid] = 0.0f;

    // ---- per-target metadata (threads 0..7) ----
    if (tid < NT) {
        const float* tg = targets + ((size_t)b * NT + tid) * 5;
        float cls = tg[0], tx = tg[1], ty = tg[2], tw = tg[3], th = tg[4];
        int gx = (int)floorf(tx * (float)GW);
        int gy = (int)floorf(ty * (float)GH);
        float best_iou = -1.0f; int best_a = 0;
        #pragma unroll
        for (int a = 0; a < 3; ++a) {
            float aw = anchors[2*a], ah = anchors[2*a+1];
            float inter = fminf(tw, aw) * fminf(th, ah);
            float uni   = tw*th + aw*ah - inter;
            float iou   = inter / (uni + 1e-6f);
            if (iou > best_iou) { best_iou = iou; best_a = a; }  // first-max wins
        }
        int valid = (gx < GW) && (gy < GH) && (best_iou >= IOU_THR);
        int gxc = min(max(gx, 0), GW-1);
        int gyc = min(max(gy, 0), GH-1);
        float aw_s = anchors[2*best_a], ah_s = anchors[2*best_a+1];
        stgt[tid][0] = tx * (float)GW - (float)gx;
        stgt[tid][1] = ty * (float)GH - (float)gy;
        stgt[tid][2] = logf(tw / aw_s + 1e-6f);
        stgt[tid][3] = logf(th / ah_s + 1e-6f);
        scls[tid]   = (int)cls;
        svalid[tid] = valid;
        slo[tid]    = valid ? best_a * CPA : (1 << 28);
        syx[tid]    = valid ? gyc * GW + gxc : -1;
    }
    __syncthreads();

    // ---- build yx bitmask + per-yx target LUT (thread 0) ----
    if (tid == 0) {
        unsigned long long m = 0;
        #pragma unroll
        for (int i = 0; i < 52; ++i) tmask[i] = 0;
        #pragma unroll
        for (int t = 0; t < NT; ++t) {
            int yx = syx[t];
            if (yx >= 0) { m |= 1ull << yx; tmask[yx] |= (unsigned char)(1u << t); }
        }
        ymask_sh = m;
    }
    __syncthreads();
    const unsigned long long ymask = ymask_sh;
    // extend: bits 50..53 replicate bits 0..3 so a 4-wide window wraps cleanly
    const unsigned long long ymext = ymask | ((ymask & 0xFull) << 50);

    // ---- stream the batch slice once (float4, 16B-aligned via parity skip) ----
    const int s0 = (b & 1) << 1;                       // odd b: start at element 2
    const float* base = preds + (size_t)b * SLICE;
    const float4* src4 = reinterpret_cast<const float4*>(base + s0);
    float s_local = 0.0f;

    auto process = [&](float4 v, int f) {
        int e0  = s0 + (f << 2);
        int ci0 = e0 / HW;
        int yx0 = e0 - ci0 * HW;
        unsigned m4 = (unsigned)(ymext >> yx0) & 0xFu;
        bool objf = (ci0==4)|(ci0==89)|(ci0==174)|(ci0==3)|(ci0==88)|(ci0==173);
        float vv[4] = {v.x, v.y, v.z, v.w};
        if (objf) {            // rare: obj channel in window
            int ci = ci0, yx = yx0;
            #pragma unroll
            for (int j = 0; j < 4; ++j) {
                if (ci==4 || ci==89 || ci==174) s_local += softplusf(sigmoidf(vv[j]));
                if (++yx == HW) { yx = 0; ++ci; }
            }
        }
        if (m4) {              // some element's cell matches some target's cell
            int ci = ci0, yx = yx0;
            #pragma unroll
            for (int j = 0; j < 4; ++j) {
                if ((m4 >> j) & 1u) {
                    unsigned tb = tmask[yx];
                    while (tb) {
                        int t = __builtin_ctz(tb); tb &= tb - 1;
                        unsigned cc = (unsigned)(ci - slo[t]);
                        if (cc < (unsigned)CPA) ptile[t][cc] = vv[j];
                    }
                }
                if (++yx == HW) { yx = 0; ++ci; }
            }
        }
    };

    // 3187 = 12*256 + 115 : 6 unrolled-by-2 rounds + tail
    int f = tid;
    for (int k = 0; k < 6; ++k) {
        float4 va = src4[f];
        float4 vb = src4[f + 256];
        process(va, f);
        process(vb, f + 256);
        f += 512;
    }
    if (f < NF4) process(src4[f], f);

    // 2 leftover scalar elements (start for odd b, end for even b)
    if (tid < 2) {
        int e = (b & 1) ? tid : (12748 + tid);
        float vv = base[e];
        int ci = e / HW, yx = e - ci * HW;
        if (ci==4 || ci==89 || ci==174) s_local += softplusf(sigmoidf(vv));
        unsigned tb = ((ymask >> yx) & 1ull) ? (unsigned)tmask[yx] : 0u;
        while (tb) {
            int t = __builtin_ctz(tb); tb &= tb - 1;
            unsigned cc = (unsigned)(ci - slo[t]);
            if (cc < (unsigned)CPA) ptile[t][cc] = vv;
        }
    }

    // ---- reduce S[b] ----
    #pragma unroll
    for (int off = 32; off > 0; off >>= 1) s_local += __shfl_xor(s_local, off);
    const int wid = tid >> 6, lane = tid & 63;
    if (lane == 0) wsum[wid] = s_local;
    __syncthreads();
    if (tid == 0) Ssh = wsum[0] + wsum[1] + wsum[2] + wsum[3];
    __syncthreads();
    const float S = Ssh;

    // ---- per-target losses: one wave per target ----
    for (int t = wid; t < NT; t += 4) {
        if (!svalid[t]) continue;
        float v0 = ptile[t][lane];                                  // ch 0..63
        float v1 = (lane < CPA - 64) ? ptile[t][64 + lane] : 0.0f;  // ch 64..84
        float m = -INFINITY;
        if (lane >= 5)        m = v0;
        if (lane < CPA - 64)  m = fmaxf(m, v1);
        #pragma unroll
        for (int off = 32; off > 0; off >>= 1) m = fmaxf(m, __shfl_xor(m, off));
        float s = 0.0f, csq = 0.0f;
        if (lane >= 5)        s += expf(v0 - m);
        if (lane < CPA - 64)  s += expf(v1 - m);
        if (lane < 4) { float d = v0 - stgt[t][lane]; csq = d * d; }
        #pragma unroll
        for (int off = 32; off > 0; off >>= 1) {
            s   += __shfl_xor(s, off);
            csq += __shfl_xor(csq, off);
        }
        float p4 = __shfl(v0, 4);
        int cch = 5 + scls[t];
        float pl = (cch < 64) ? __shfl(v0, cch) : __shfl(v1, cch - 64);
        float ce = m + logf(s) - pl;
        float z    = sigmoidf(p4);
        float spz  = softplusf(z);
        float spnz = softplusf(-z);
        if (lane == 0) {
            atomicAdd(&accS[0], csq);
            atomicAdd(&accS[1], spnz);
            atomicAdd(&accS[2], S - spz);
            atomicAdd(&accS[3], ce);
        }
    }
    __syncthreads();
    if (tid < 4) atomicAdd(&acc[tid], accS[tid]);
}

__global__ void yolo_final(const float* __restrict__ acc,
                           float* __restrict__ out, float denom) {
    if (threadIdx.x == 0 && blockIdx.x == 0) {
        float lc   = acc[0] / denom;
        float lo   = acc[1];
        float ln   = 0.5f * acc[2];
        float lcls = acc[3] / denom;
        float tot  = 5.0f * lc + lo + 0.5f * ln + lcls;
        out[0] = tot; out[1] = lc; out[2] = lo; out[3] = ln; out[4] = lcls;
    }
}

extern "C" void kernel_launch(void* const* d_in, const int* in_sizes, int n_in,
                              void* d_out, int out_size, void* d_ws, size_t ws_size,
                              hipStream_t stream) {
    const float* preds   = (const float*)d_in[0];
    const float* targets = (const float*)d_in[1];
    const float* anchors = (const float*)d_in[2];
    float* out = (float*)d_out;
    float* acc = (float*)d_ws;

    int B = in_sizes[0] / SLICE;   // 4096

    hipMemsetAsync(acc, 0, 4 * sizeof(float), stream);
    yolo_main<<<B, 256, 0, stream>>>(preds, targets, anchors, acc);
    yolo_final<<<1, 64, 0, stream>>>(acc, out, (float)B * (float)NT);
}

// Round 3
// 82.438 us; speedup vs baseline: 1.1396x; 1.1396x over previous
//
#include <hip/hip_runtime.h>
#include <math.h>

#define GH 5
#define GW 10
#define HW 50            // GH*GW
#define CPA 85           // channels per anchor (5 + 80)
#define SLICE 12750      // 255 * 50 floats per batch
#define NT 8             // targets per batch
#define IOU_THR 0.3f

__device__ __forceinline__ float softplusf(float x) {
    return fmaxf(x, 0.0f) + log1pf(expf(-fabsf(x)));   // log(1+e^x), stable
}
__device__ __forceinline__ float sigmoidf(float x) {
    return 1.0f / (1.0f + expf(-x));
}

__global__ __launch_bounds__(256) void yolo_main(
    const float* __restrict__ preds,
    const float* __restrict__ targets,
    const float* __restrict__ anchors,
    float* __restrict__ acc)   // acc[0]=coord_raw acc[1]=obj acc[2]=noobj_raw acc[3]=cls_raw
{
    __shared__ float ptile[NT][88];   // gathered 85 channels per target
    __shared__ float stgt[NT][4];
    __shared__ int   slo[NT];         // first global-channel of best anchor (0 if invalid)
    __shared__ int   syx[NT];         // clamped cell index (0 if invalid)
    __shared__ int   scls[NT];
    __shared__ int   svalid[NT];
    __shared__ float Ssh;
    __shared__ float wsum[4];
    __shared__ float accS[4];

    const int b   = blockIdx.x;
    const int tid = threadIdx.x;
    const float* base = preds + (size_t)b * SLICE;

    // ---- obj channels (4 / 89 / 174): 150 loads, independent of metadata ----
    float s_local = 0.0f;
    if (tid < 150) {
        int a  = tid / 50;
        int yx = tid - a * 50;
        float v = base[(a * CPA + 4) * HW + yx];
        s_local = softplusf(sigmoidf(v));
    }

    if (tid < 4) accS[tid] = 0.0f;

    // ---- per-target metadata (threads 0..7) ----
    if (tid < NT) {
        const float* tg = targets + ((size_t)b * NT + tid) * 5;
        float cls = tg[0], tx = tg[1], ty = tg[2], tw = tg[3], th = tg[4];
        int gx = (int)floorf(tx * (float)GW);
        int gy = (int)floorf(ty * (float)GH);
        float best_iou = -1.0f; int best_a = 0;
        #pragma unroll
        for (int a = 0; a < 3; ++a) {
            float aw = anchors[2*a], ah = anchors[2*a+1];
            float inter = fminf(tw, aw) * fminf(th, ah);
            float uni   = tw*th + aw*ah - inter;
            float iou   = inter / (uni + 1e-6f);
            if (iou > best_iou) { best_iou = iou; best_a = a; }  // first-max wins
        }
        int valid = (gx < GW) && (gy < GH) && (best_iou >= IOU_THR);
        int gxc = min(max(gx, 0), GW-1);
        int gyc = min(max(gy, 0), GH-1);
        float aw_s = anchors[2*best_a], ah_s = anchors[2*best_a+1];
        stgt[tid][0] = tx * (float)GW - (float)gx;
        stgt[tid][1] = ty * (float)GH - (float)gy;
        stgt[tid][2] = logf(tw / aw_s + 1e-6f);
        stgt[tid][3] = logf(th / ah_s + 1e-6f);
        scls[tid]   = (int)cls;
        svalid[tid] = valid;
        slo[tid]    = valid ? best_a * CPA : 0;   // 0 keeps gather in-bounds
        syx[tid]    = valid ? gyc * GW + gxc : 0;
    }
    __syncthreads();

    // ---- direct gather: 680 scattered scalar loads (3 rounds) ----
    #pragma unroll
    for (int i = tid; i < NT * CPA; i += 256) {
        int t  = i / CPA;
        int cc = i - t * CPA;
        ptile[t][cc] = base[(slo[t] + cc) * HW + syx[t]];
    }

    // ---- reduce S[b] (overlaps with gather latency) ----
    #pragma unroll
    for (int off = 32; off > 0; off >>= 1) s_local += __shfl_xor(s_local, off);
    const int wid = tid >> 6, lane = tid & 63;
    if (lane == 0) wsum[wid] = s_local;
    __syncthreads();            // also publishes ptile
    if (tid == 0) Ssh = wsum[0] + wsum[1] + wsum[2] + wsum[3];
    __syncthreads();
    const float S = Ssh;

    // ---- per-target losses: one wave per target (4 waves x 2 rounds) ----
    for (int t = wid; t < NT; t += 4) {
        if (!svalid[t]) continue;
        float v0 = ptile[t][lane];                                  // ch 0..63
        float v1 = (lane < CPA - 64) ? ptile[t][64 + lane] : 0.0f;  // ch 64..84
        // logsumexp over class logits (ch 5..84)
        float m = -INFINITY;
        if (lane >= 5)        m = v0;
        if (lane < CPA - 64)  m = fmaxf(m, v1);
        #pragma unroll
        for (int off = 32; off > 0; off >>= 1) m = fmaxf(m, __shfl_xor(m, off));
        float s = 0.0f, csq = 0.0f;
        if (lane >= 5)        s += expf(v0 - m);
        if (lane < CPA - 64)  s += expf(v1 - m);
        if (lane < 4) { float d = v0 - stgt[t][lane]; csq = d * d; }
        #pragma unroll
        for (int off = 32; off > 0; off >>= 1) {
            s   += __shfl_xor(s, off);
            csq += __shfl_xor(csq, off);
        }
        float p4 = __shfl(v0, 4);
        int cch = 5 + scls[t];
        float pl = (cch < 64) ? __shfl(v0, cch) : __shfl(v1, cch - 64);
        float ce = m + logf(s) - pl;
        float z    = sigmoidf(p4);
        float spz  = softplusf(z);
        float spnz = softplusf(-z);
        if (lane == 0) {
            atomicAdd(&accS[0], csq);
            atomicAdd(&accS[1], spnz);
            atomicAdd(&accS[2], S - spz);
            atomicAdd(&accS[3], ce);
        }
    }
    __syncthreads();
    if (tid < 4) atomicAdd(&acc[tid], accS[tid]);
}

__global__ void yolo_final(const float* __restrict__ acc,
                           float* __restrict__ out, float denom) {
    if (threadIdx.x == 0 && blockIdx.x == 0) {
        float lc   = acc[0] / denom;
        float lo   = acc[1];
        float ln   = 0.5f * acc[2];
        float lcls = acc[3] / denom;
        float tot  = 5.0f * lc + lo + 0.5f * ln + lcls;
        out[0] = tot; out[1] = lc; out[2] = lo; out[3] = ln; out[4] = lcls;
    }
}

extern "C" void kernel_launch(void* const* d_in, const int* in_sizes, int n_in,
                              void* d_out, int out_size, void* d_ws, size_t ws_size,
                              hipStream_t stream) {
    const float* preds   = (const float*)d_in[0];
    const float* targets = (const float*)d_in[1];
    const float* anchors = (const float*)d_in[2];
    float* out = (float*)d_out;
    float* acc = (float*)d_ws;

    int B = in_sizes[0] / SLICE;   // 4096

    hipMemsetAsync(acc, 0, 4 * sizeof(float), stream);
    yolo_main<<<B, 256, 0, stream>>>(preds, targets, anchors, acc);
    yolo_final<<<1, 64, 0, stream>>>(acc, out, (float)B * (float)NT);
}

// Round 4
// 42.515 us; speedup vs baseline: 2.2096x; 1.9390x over previous
//
#include <hip/hip_runtime.h>
#include <math.h>

#define GH 5
#define GW 10
#define HW 50            // GH*GW
#define CPA 85           // channels per anchor (5 + 80)
#define SLICE 12750      // 255 * 50 floats per batch
#define NT 8             // targets per batch
#define IOU_THR 0.3f

__device__ __forceinline__ float softplusf(float x) {
    return fmaxf(x, 0.0f) + log1pf(expf(-fabsf(x)));   // log(1+e^x), stable
}
__device__ __forceinline__ float sigmoidf(float x) {
    return 1.0f / (1.0f + expf(-x));
}

__global__ __launch_bounds__(256) void yolo_main(
    const float* __restrict__ preds,
    const float* __restrict__ targets,
    const float* __restrict__ anchors,
    float* __restrict__ part)  // part[b*4+0..3] = coord_raw, obj, noobj_raw, cls_raw
{
    __shared__ float ptile[NT][88];   // gathered 85 channels per target
    __shared__ float stgt[NT][4];
    __shared__ int   slo[NT];         // first global-channel of best anchor (0 if invalid)
    __shared__ int   syx[NT];         // clamped cell index (0 if invalid)
    __shared__ int   scls[NT];
    __shared__ int   svalid[NT];
    __shared__ float Ssh;
    __shared__ float wsum[4];
    __shared__ float accS[4];

    const int b   = blockIdx.x;
    const int tid = threadIdx.x;
    const float* base = preds + (size_t)b * SLICE;

    // ---- obj channels (4 / 89 / 174): 150 loads, independent of metadata ----
    float s_local = 0.0f;
    if (tid < 150) {
        int a  = tid / 50;
        int yx = tid - a * 50;
        float v = base[(a * CPA + 4) * HW + yx];
        s_local = softplusf(sigmoidf(v));
    }

    if (tid < 4) accS[tid] = 0.0f;

    // ---- per-target metadata (threads 0..7) ----
    if (tid < NT) {
        const float* tg = targets + ((size_t)b * NT + tid) * 5;
        float cls = tg[0], tx = tg[1], ty = tg[2], tw = tg[3], th = tg[4];
        int gx = (int)floorf(tx * (float)GW);
        int gy = (int)floorf(ty * (float)GH);
        float best_iou = -1.0f; int best_a = 0;
        #pragma unroll
        for (int a = 0; a < 3; ++a) {
            float aw = anchors[2*a], ah = anchors[2*a+1];
            float inter = fminf(tw, aw) * fminf(th, ah);
            float uni   = tw*th + aw*ah - inter;
            float iou   = inter / (uni + 1e-6f);
            if (iou > best_iou) { best_iou = iou; best_a = a; }  // first-max wins
        }
        int valid = (gx < GW) && (gy < GH) && (best_iou >= IOU_THR);
        int gxc = min(max(gx, 0), GW-1);
        int gyc = min(max(gy, 0), GH-1);
        float aw_s = anchors[2*best_a], ah_s = anchors[2*best_a+1];
        stgt[tid][0] = tx * (float)GW - (float)gx;
        stgt[tid][1] = ty * (float)GH - (float)gy;
        stgt[tid][2] = logf(tw / aw_s + 1e-6f);
        stgt[tid][3] = logf(th / ah_s + 1e-6f);
        scls[tid]   = (int)cls;
        svalid[tid] = valid;
        slo[tid]    = valid ? best_a * CPA : 0;   // 0 keeps gather in-bounds
        syx[tid]    = valid ? gyc * GW + gxc : 0;
    }
    __syncthreads();

    // ---- direct gather: 680 scattered scalar loads (3 rounds) ----
    #pragma unroll
    for (int i = tid; i < NT * CPA; i += 256) {
        int t  = i / CPA;
        int cc = i - t * CPA;
        ptile[t][cc] = base[(slo[t] + cc) * HW + syx[t]];
    }

    // ---- reduce S[b] (overlaps with gather latency) ----
    #pragma unroll
    for (int off = 32; off > 0; off >>= 1) s_local += __shfl_xor(s_local, off);
    const int wid = tid >> 6, lane = tid & 63;
    if (lane == 0) wsum[wid] = s_local;
    __syncthreads();            // also publishes ptile
    if (tid == 0) Ssh = wsum[0] + wsum[1] + wsum[2] + wsum[3];
    __syncthreads();
    const float S = Ssh;

    // ---- per-target losses: one wave per target (4 waves x 2 rounds) ----
    for (int t = wid; t < NT; t += 4) {
        if (!svalid[t]) continue;
        float v0 = ptile[t][lane];                                  // ch 0..63
        float v1 = (lane < CPA - 64) ? ptile[t][64 + lane] : 0.0f;  // ch 64..84
        // logsumexp over class logits (ch 5..84)
        float m = -INFINITY;
        if (lane >= 5)        m = v0;
        if (lane < CPA - 64)  m = fmaxf(m, v1);
        #pragma unroll
        for (int off = 32; off > 0; off >>= 1) m = fmaxf(m, __shfl_xor(m, off));
        float s = 0.0f, csq = 0.0f;
        if (lane >= 5)        s += expf(v0 - m);
        if (lane < CPA - 64)  s += expf(v1 - m);
        if (lane < 4) { float d = v0 - stgt[t][lane]; csq = d * d; }
        #pragma unroll
        for (int off = 32; off > 0; off >>= 1) {
            s   += __shfl_xor(s, off);
            csq += __shfl_xor(csq, off);
        }
        float p4 = __shfl(v0, 4);
        int cch = 5 + scls[t];
        float pl = (cch < 64) ? __shfl(v0, cch) : __shfl(v1, cch - 64);
        float ce = m + logf(s) - pl;
        float z    = sigmoidf(p4);
        float spz  = softplusf(z);
        float spnz = softplusf(-z);
        if (lane == 0) {
            atomicAdd(&accS[0], csq);        // LDS atomics — cheap
            atomicAdd(&accS[1], spnz);
            atomicAdd(&accS[2], S - spz);
            atomicAdd(&accS[3], ce);
        }
    }
    __syncthreads();
    // ---- plain per-block store: NO global atomics ----
    if (tid < 4) part[(size_t)b * 4 + tid] = accS[tid];
}

__global__ __launch_bounds__(1024) void yolo_reduce(
    const float4* __restrict__ part, int nb,
    float* __restrict__ out, float denom)
{
    __shared__ float wsum[16][4];
    float c0 = 0.f, c1 = 0.f, c2 = 0.f, c3 = 0.f;
    for (int i = threadIdx.x; i < nb; i += 1024) {
        float4 v = part[i];
        c0 += v.x; c1 += v.y; c2 += v.z; c3 += v.w;
    }
    #pragma unroll
    for (int off = 32; off > 0; off >>= 1) {
        c0 += __shfl_xor(c0, off); c1 += __shfl_xor(c1, off);
        c2 += __shfl_xor(c2, off); c3 += __shfl_xor(c3, off);
    }
    int w = threadIdx.x >> 6;
    if ((threadIdx.x & 63) == 0) {
        wsum[w][0] = c0; wsum[w][1] = c1; wsum[w][2] = c2; wsum[w][3] = c3;
    }
    __syncthreads();
    if (threadIdx.x == 0) {
        float a0 = 0.f, a1 = 0.f, a2 = 0.f, a3 = 0.f;
        #pragma unroll
        for (int i = 0; i < 16; ++i) {
            a0 += wsum[i][0]; a1 += wsum[i][1]; a2 += wsum[i][2]; a3 += wsum[i][3];
        }
        float lc   = a0 / denom;
        float lo   = a1;
        float ln   = 0.5f * a2;
        float lcls = a3 / denom;
        float tot  = 5.0f * lc + lo + 0.5f * ln + lcls;
        out[0] = tot; out[1] = lc; out[2] = lo; out[3] = ln; out[4] = lcls;
    }
}

extern "C" void kernel_launch(void* const* d_in, const int* in_sizes, int n_in,
                              void* d_out, int out_size, void* d_ws, size_t ws_size,
                              hipStream_t stream) {
    const float* preds   = (const float*)d_in[0];
    const float* targets = (const float*)d_in[1];
    const float* anchors = (const float*)d_in[2];
    float* out  = (float*)d_out;
    float* part = (float*)d_ws;           // 4 floats per block, fully overwritten

    int B = in_sizes[0] / SLICE;   // 4096

    yolo_main<<<B, 256, 0, stream>>>(preds, targets, anchors, part);
    yolo_reduce<<<1, 1024, 0, stream>>>((const float4*)part, B, out, (float)B * (float)NT);
}

// Round 5
// 40.954 us; speedup vs baseline: 2.2938x; 1.0381x over previous
//
#include <hip/hip_runtime.h>
#include <math.h>

#define GH 5
#define GW 10
#define HW 50            // GH*GW
#define CPA 85           // channels per anchor (5 + 80)
#define SLICE 12750      // 255 * 50 floats per batch
#define NT 8             // targets per batch
#define IOU_THR 0.3f

__device__ __forceinline__ float softplusf(float x) {
    return fmaxf(x, 0.0f) + log1pf(expf(-fabsf(x)));   // log(1+e^x), stable
}
__device__ __forceinline__ float sigmoidf(float x) {
    return 1.0f / (1.0f + expf(-x));
}

// Two batches per block: more loads in flight per thread, half the
// barrier/epilogue overhead per byte fetched.
__global__ __launch_bounds__(256) void yolo_main(
    const float* __restrict__ preds,
    const float* __restrict__ targets,
    const float* __restrict__ anchors,
    float* __restrict__ part, int B)   // part[b*4+..] = coord_raw, obj, noobj_raw, cls_raw
{
    __shared__ float ptile[16][88];   // 85 gathered channels x 16 targets (2 batches)
    __shared__ float stgt[16][4];
    __shared__ int   sptr[16];        // element offset of channel-0 for best anchor at cell
    __shared__ int   scls[16];
    __shared__ int   svalid[16];
    __shared__ float Ssh[2];
    __shared__ float wsum[4][2];
    __shared__ float accS[2][4];

    const int  b0   = blockIdx.x * 2;
    const int  b1   = b0 + 1;
    const bool has2 = (b1 < B);
    const int  tid  = threadIdx.x;
    const float* base0 = preds + (size_t)b0 * SLICE;
    const float* base1 = preds + (size_t)(has2 ? b1 : b0) * SLICE;

    if (tid < 8) accS[tid >> 2][tid & 3] = 0.0f;

    // ---- issue obj-channel loads RAW (300 loads, 2 per thread max) ----
    float ov0 = 0.0f, ov1a = 0.0f, ov1b = 0.0f;
    {
        if (tid < 150) {
            int a = tid / 50, yx = tid - a * 50;
            ov0 = base0[(a * CPA + 4) * HW + yx];
        } else {
            int k = tid - 150;                 // 0..105
            int a = k / 50, yx = k - a * 50;
            ov1a = base1[(a * CPA + 4) * HW + yx];
        }
        if (tid < 44) {                        // batch1 idx 106..149
            int k = tid + 106;
            int a = k / 50, yx = k - a * 50;
            ov1b = base1[(a * CPA + 4) * HW + yx];
        }
    }

    // ---- per-target metadata (threads 0..15) ----
    if (tid < 16) {
        int bb = tid >> 3, tt = tid & 7;
        int bidx = bb ? (has2 ? b1 : b0) : b0;
        const float* tg = targets + ((size_t)bidx * NT + tt) * 5;
        float cls = tg[0], tx = tg[1], ty = tg[2], tw = tg[3], th = tg[4];
        int gx = (int)floorf(tx * (float)GW);
        int gy = (int)floorf(ty * (float)GH);
        float best_iou = -1.0f; int best_a = 0;
        #pragma unroll
        for (int a = 0; a < 3; ++a) {
            float aw = anchors[2*a], ah = anchors[2*a+1];
            float inter = fminf(tw, aw) * fminf(th, ah);
            float uni   = tw*th + aw*ah - inter;
            float iou   = inter / (uni + 1e-6f);
            if (iou > best_iou) { best_iou = iou; best_a = a; }  // first-max wins
        }
        int valid = (gx < GW) && (gy < GH) && (best_iou >= IOU_THR) && (bb == 0 || has2);
        int gxc = min(max(gx, 0), GW-1);
        int gyc = min(max(gy, 0), GH-1);
        float aw_s = anchors[2*best_a], ah_s = anchors[2*best_a+1];
        stgt[tid][0] = tx * (float)GW - (float)gx;
        stgt[tid][1] = ty * (float)GH - (float)gy;
        stgt[tid][2] = logf(tw / aw_s + 1e-6f);
        stgt[tid][3] = logf(th / ah_s + 1e-6f);
        scls[tid]   = (int)cls;
        svalid[tid] = valid;
        sptr[tid]   = valid ? (best_a * CPA * HW + gyc * GW + gxc) : 0;
    }
    __syncthreads();

    // ---- direct gather: 1360 scattered loads, 5 unrolled + tail ----
    {
        int i = tid;
        #pragma unroll
        for (int k = 0; k < 5; ++k) {
            int t = i / CPA, cc = i - t * CPA;
            const float* bp = (t >= 8) ? base1 : base0;
            ptile[t][cc] = bp[sptr[t] + cc * HW];
            i += 256;
        }
        if (i < 16 * CPA) {
            int t = i / CPA, cc = i - t * CPA;
            const float* bp = (t >= 8) ? base1 : base0;
            ptile[t][cc] = bp[sptr[t] + cc * HW];
        }
    }

    // ---- obj softplus + reduce S (hides under gather-load latency) ----
    float s0 = 0.0f, s1 = 0.0f;
    if (tid < 150) s0 = softplusf(sigmoidf(ov0));
    else           s1 = softplusf(sigmoidf(ov1a));
    if (tid < 44)  s1 += softplusf(sigmoidf(ov1b));
    #pragma unroll
    for (int off = 32; off > 0; off >>= 1) {
        s0 += __shfl_xor(s0, off);
        s1 += __shfl_xor(s1, off);
    }
    const int wid = tid >> 6, lane = tid & 63;
    if (lane == 0) { wsum[wid][0] = s0; wsum[wid][1] = s1; }
    __syncthreads();            // also publishes ptile
    if (tid < 2) Ssh[tid] = wsum[0][tid] + wsum[1][tid] + wsum[2][tid] + wsum[3][tid];
    __syncthreads();

    // ---- per-target losses: one wave per target (4 waves x 4 rounds) ----
    for (int t = wid; t < 16; t += 4) {
        if (!svalid[t]) continue;
        float v0 = ptile[t][lane];                                  // ch 0..63
        float v1 = (lane < CPA - 64) ? ptile[t][64 + lane] : 0.0f;  // ch 64..84
        float m = -INFINITY;
        if (lane >= 5)        m = v0;
        if (lane < CPA - 64)  m = fmaxf(m, v1);
        #pragma unroll
        for (int off = 32; off > 0; off >>= 1) m = fmaxf(m, __shfl_xor(m, off));
        float s = 0.0f, csq = 0.0f;
        if (lane >= 5)        s += expf(v0 - m);
        if (lane < CPA - 64)  s += expf(v1 - m);
        if (lane < 4) { float d = v0 - stgt[t][lane]; csq = d * d; }
        #pragma unroll
        for (int off = 32; off > 0; off >>= 1) {
            s   += __shfl_xor(s, off);
            csq += __shfl_xor(csq, off);
        }
        float p4 = __shfl(v0, 4);
        int cch = 5 + scls[t];
        float pl = (cch < 64) ? __shfl(v0, cch) : __shfl(v1, cch - 64);
        float ce = m + logf(s) - pl;
        float z    = sigmoidf(p4);
        float spz  = softplusf(z);
        float spnz = softplusf(-z);
        if (lane == 0) {
            int bb = t >> 3;
            atomicAdd(&accS[bb][0], csq);          // LDS atomics — cheap
            atomicAdd(&accS[bb][1], spnz);
            atomicAdd(&accS[bb][2], Ssh[bb] - spz);
            atomicAdd(&accS[bb][3], ce);
        }
    }
    __syncthreads();
    // ---- plain per-block stores: NO global atomics ----
    if (tid < 4)                    part[(size_t)b0 * 4 + tid]       = accS[0][tid];
    else if (tid < 8 && has2)       part[(size_t)b1 * 4 + (tid - 4)] = accS[1][tid - 4];
}

__global__ __launch_bounds__(1024) void yolo_reduce(
    const float4* __restrict__ part, int nb,
    float* __restrict__ out, float denom)
{
    __shared__ float wsum[16][4];
    float c0 = 0.f, c1 = 0.f, c2 = 0.f, c3 = 0.f;
    for (int i = threadIdx.x; i < nb; i += 1024) {
        float4 v = part[i];
        c0 += v.x; c1 += v.y; c2 += v.z; c3 += v.w;
    }
    #pragma unroll
    for (int off = 32; off > 0; off >>= 1) {
        c0 += __shfl_xor(c0, off); c1 += __shfl_xor(c1, off);
        c2 += __shfl_xor(c2, off); c3 += __shfl_xor(c3, off);
    }
    int w = threadIdx.x >> 6;
    if ((threadIdx.x & 63) == 0) {
        wsum[w][0] = c0; wsum[w][1] = c1; wsum[w][2] = c2; wsum[w][3] = c3;
    }
    __syncthreads();
    if (threadIdx.x == 0) {
        float a0 = 0.f, a1 = 0.f, a2 = 0.f, a3 = 0.f;
        #pragma unroll
        for (int i = 0; i < 16; ++i) {
            a0 += wsum[i][0]; a1 += wsum[i][1]; a2 += wsum[i][2]; a3 += wsum[i][3];
        }
        float lc   = a0 / denom;
        float lo   = a1;
        float ln   = 0.5f * a2;
        float lcls = a3 / denom;
        float tot  = 5.0f * lc + lo + 0.5f * ln + lcls;
        out[0] = tot; out[1] = lc; out[2] = lo; out[3] = ln; out[4] = lcls;
    }
}

extern "C" void kernel_launch(void* const* d_in, const int* in_sizes, int n_in,
                              void* d_out, int out_size, void* d_ws, size_t ws_size,
                              hipStream_t stream) {
    const float* preds   = (const float*)d_in[0];
    const float* targets = (const float*)d_in[1];
    const float* anchors = (const float*)d_in[2];
    float* out  = (float*)d_out;
    float* part = (float*)d_ws;           // 4 floats per batch, fully overwritten

    int B = in_sizes[0] / SLICE;   // 4096
    int grid = (B + 1) / 2;        // 2 batches per block

    yolo_main<<<grid, 256, 0, stream>>>(preds, targets, anchors, part, B);
    yolo_reduce<<<1, 1024, 0, stream>>>((const float4*)part, B, out, (float)B * (float)NT);
}